// Round 7
// baseline (152.001 us; speedup 1.0000x reference)
//
#include <hip/hip_runtime.h>
#include <cmath>

#define NCLUST 64
#define TSTEPS 32
#define BATCH  64
#define DIM    4096
#define NTH    256
#define GPR    16                // blocks (groups) per batch row
#define REFRAC 2

// Raw barrier: drain LDS ops only; global stores/loads keep streaming.
#define BAR() do {                                              \
    __builtin_amdgcn_sched_barrier(0);                          \
    asm volatile("s_waitcnt lgkmcnt(0)" ::: "memory");          \
    __builtin_amdgcn_s_barrier();                               \
    __builtin_amdgcn_sched_barrier(0);                          \
} while (0)

#define LDSFENCE() do {                                         \
    __builtin_amdgcn_sched_barrier(0);                          \
    asm volatile("s_waitcnt lgkmcnt(0)" ::: "memory");          \
    __builtin_amdgcn_sched_barrier(0);                          \
} while (0)

// Grid: 1024 blocks of 256 threads. blockIdx = b + 64*g  (b = row, g = group)
// -> all 16 blocks of row b share XCD b%8 under round-robin dispatch (perf
// heuristic only). Thread owns neuron d = g*256 + tid; cluster(d) = tid&63
// = lane. Parity-monotonic mailboxes gCnt[b][t&1][c]: per step, each block's
// wave 0 adds (block_count | 1<<20) to its row's parity word; step t's counts
// are complete when arrivals >= 16*(t/2+1). Steps t and t+1 use different
// words, and a t+2 publish to parity p is causally ordered after every
// block's final step-t read of that word (poll of t+1 requires all t+1
// publishes, each program-after that block's t read) -> race-free, and the
// 128 words/row stay hot at the coherence point for the whole kernel.
// After the single per-step barrier: wave 0 publishes, ALL waves poll
// (lane l polls cluster l's word), bounce the 64 counts through a private
// per-wave LDS strip (wave-synchronous, no barrier), and each lane's 64-FMA
// matvec accumulator IS the cascade for its own neuron. No second barrier,
// cascade never touches LDS.
__global__ __launch_bounds__(NTH, 4)
void alif_fwd(const float* __restrict__ x_in,      // (T,B,D)
              const float* __restrict__ threshold, // (D)
              const float* __restrict__ bm_raw,    // scalar
              const float* __restrict__ bs_raw,    // scalar
              const float* __restrict__ nw,        // (NC,NC)
              const float* __restrict__ gain,      // (NC)
              float* __restrict__ out_s,           // (T,B,D)
              float* __restrict__ out_v,           // (T,B,D)
              unsigned int* __restrict__ gCnt)     // (B,2,NC) parity mailboxes
{
    __shared__ unsigned int sCnt[2][NCLUST];            // per-parity block counts
    __shared__ __align__(16) float sB[NTH / 64][NCLUST]; // per-wave count bounce

    const int tid  = threadIdx.x;
    const int lane = tid & 63;
    const int wav  = tid >> 6;
    const int b    = blockIdx.x & 63;
    const int g    = blockIdx.x >> 6;

    // Per-lane W row: sigmoid(nw[lane][c]) * gain[lane] / 64 (used by all waves)
    float wReg[NCLUST];
    {
        const float gv_ = gain[lane] * (1.0f / 64.0f);
#pragma unroll
        for (int k = 0; k < 16; k++) {
            float4 w4 = *(const float4*)(nw + lane * NCLUST + 4 * k);
            wReg[4*k+0] = gv_ / (1.0f + expf(-w4.x));
            wReg[4*k+1] = gv_ / (1.0f + expf(-w4.y));
            wReg[4*k+2] = gv_ / (1.0f + expf(-w4.z));
            wReg[4*k+3] = gv_ / (1.0f + expf(-w4.w));
        }
    }
    const float beta_m = 1.0f / (1.0f + expf(-bm_raw[0]));
    const float beta_s = 1.0f / (1.0f + expf(-bs_raw[0]));
    const float ombm   = 1.0f - beta_m;
    const float vreset = -0.1f;

    const int d0 = g * NTH + tid;
    const float th = threshold[d0];
    float v = 0.f, is = 0.f;
    int   r = 0;

    const size_t strideT = (size_t)BATCH * DIM;
    const float* xp = x_in  + (size_t)b * DIM + d0;
    float*       sp = out_s + (size_t)b * DIM + d0;
    float*       vp = out_v + (size_t)b * DIM + d0;

    float xA = xp[0];
    float xB = xp[strideT];

    if (tid < 2 * NCLUST) ((unsigned int*)sCnt)[tid] = 0u;
    __syncthreads();

    float casc = 0.f;
    unsigned int cumPrev0 = 0u, cumPrev1 = 0u;
    unsigned int* const gw = gCnt + (size_t)b * 2 * NCLUST + lane;

#define STEP(T_, XC, P_)                                                      \
    {                                                                         \
        float isv = beta_s * (is + casc) + XC;                                \
        float vn  = beta_m * v + ombm * isv;                                  \
        float vv  = (r > 0) ? vreset : vn;                                    \
        bool  spk = (vv >= th);                                               \
        float sv  = spk ? 1.0f : 0.0f;                                        \
        v  = spk ? (vv - th) : vv;                                            \
        r  = spk ? REFRAC : ((r > 0) ? r - 1 : 0);                            \
        is = isv;                                                             \
        if (spk) atomicAdd(&sCnt[P_][lane], 1u);                              \
        sp[(size_t)(T_) * strideT] = sv;                                      \
        vp[(size_t)(T_) * strideT] = v;                                       \
        if ((T_) + 2 < TSTEPS) XC = xp[(size_t)((T_) + 2) * strideT];         \
        BAR();                                                                \
        if (wav == 0) {                                                       \
            unsigned int cnt = sCnt[P_][lane];                                \
            __hip_atomic_fetch_add(gw + (P_) * NCLUST, cnt + (1u << 20),      \
                                   __ATOMIC_RELAXED,                          \
                                   __HIP_MEMORY_SCOPE_AGENT);                 \
            sCnt[P_][lane] = 0u;            /* reused at step T_+2 */         \
        }                                                                     \
        const unsigned int tgt = (unsigned int)(GPR * (((T_) >> 1) + 1)) << 20;\
        unsigned int gv;                                                      \
        do {                                                                  \
            gv = __hip_atomic_load(gw + (P_) * NCLUST, __ATOMIC_RELAXED,      \
                                   __HIP_MEMORY_SCOPE_AGENT);                 \
        } while (!__all(gv >= tgt));                                          \
        unsigned int cum = gv & 0xFFFFFu;                                     \
        sB[wav][lane] = (float)(cum - ((P_) ? cumPrev1 : cumPrev0));          \
        if (P_) cumPrev1 = cum; else cumPrev0 = cum;                          \
        LDSFENCE();                     /* wave-synchronous bounce */         \
        {                                                                     \
            float a0 = 0.f, a1 = 0.f, a2 = 0.f, a3 = 0.f;                     \
            _Pragma("unroll")                                                 \
            for (int k = 0; k < 16; k++) {                                    \
                float4 c4 = *(const float4*)&sB[wav][4 * k];                  \
                a0 += c4.x * wReg[4*k+0];                                     \
                a1 += c4.y * wReg[4*k+1];                                     \
                a2 += c4.z * wReg[4*k+2];                                     \
                a3 += c4.w * wReg[4*k+3];                                     \
            }                                                                 \
            casc = (a0 + a1) + (a2 + a3);   /* lane l == this neuron's cluster */ \
        }                                                                     \
    }

    for (int t = 0; t < TSTEPS; t += 2) {
        STEP(t,     xA, 0)
        STEP(t + 1, xB, 1)
    }
#undef STEP
}

extern "C" void kernel_launch(void* const* d_in, const int* in_sizes, int n_in,
                              void* d_out, int out_size, void* d_ws, size_t ws_size,
                              hipStream_t stream) {
    const float* x  = (const float*)d_in[0];
    const float* th = (const float*)d_in[1];
    const float* bm = (const float*)d_in[2];
    const float* bs = (const float*)d_in[3];
    const float* nw = (const float*)d_in[4];
    const float* gn = (const float*)d_in[5];
    float* out_s = (float*)d_out;
    float* out_v = out_s + (size_t)TSTEPS * BATCH * DIM;

    // Parity mailboxes: (B, 2, NC) u32 = 32 KB, zeroed every launch
    // (deterministic; no cross-replay state).
    hipMemsetAsync(d_ws, 0, (size_t)BATCH * 2 * NCLUST * sizeof(unsigned int), stream);

    hipLaunchKernelGGL(alif_fwd, dim3(BATCH * GPR), dim3(NTH), 0, stream,
                       x, th, bm, bs, nw, gn, out_s, out_v,
                       (unsigned int*)d_ws);
}

// Round 9
// 66.859 us; speedup vs baseline: 2.2735x; 2.2735x over previous
//
#include <hip/hip_runtime.h>
#include <cmath>

#define NCLUST 64
#define TSTEPS 32
#define BATCH  64
#define DIM    4096
#define REFRAC 2

// Raw barrier: drain LDS ops only; global stores keep floating.
#define BAR() do {                                              \
    __builtin_amdgcn_sched_barrier(0);                          \
    asm volatile("s_waitcnt lgkmcnt(0)" ::: "memory");          \
    __builtin_amdgcn_s_barrier();                               \
    __builtin_amdgcn_sched_barrier(0);                          \
} while (0)

// The LIF step, shared by both kernels so spike decisions are bit-identical:
// explicit fmaf/mul -> no contraction ambiguity between compilation contexts.
__device__ __forceinline__ float lif_step(float x, float casc, float th,
                                          float beta_s, float beta_m,
                                          float ombm, float vreset,
                                          float& v, float& is, int& r)
{
    float isv = fmaf(beta_s, is + casc, x);
    float vn  = fmaf(beta_m, v, ombm * isv);
    float vv  = (r > 0) ? vreset : vn;
    bool  spk = (vv >= th);
    v  = spk ? (vv - th) : vv;
    r  = spk ? REFRAC : ((r > 0) ? r - 1 : 0);
    is = isv;
    return spk ? 1.0f : 0.0f;
}

// ---------------- Kernel A: sequential cascade precompute ----------------
// One block (1024 thr, 16 waves) per batch row; thread owns d = tid + j*1024
// (cluster = tid&63 = lane for all j). NO big outputs: per step it emits only
// the 64-float cascade vector to gCasc[t][b][*] (fire-and-forget store).
// Per step: phase1 (4x lif_step, LDS count atomic) -> BAR -> wave 0 matvec
// with W*gain/64 in VGPRs, publish cascade to LDS + global, reset counts
// -> BAR.
__global__ __launch_bounds__(1024)
void alif_casc(const float* __restrict__ x_in,      // (T,B,D)
               const float* __restrict__ threshold, // (D)
               const float* __restrict__ bm_raw,
               const float* __restrict__ bs_raw,
               const float* __restrict__ nw,        // (NC,NC)
               const float* __restrict__ gain,      // (NC)
               float* __restrict__ gCasc)           // (T,B,NC) workspace
{
    __shared__ unsigned int sCnt[NCLUST];
    __shared__ float        sCasc[NCLUST];

    const int tid  = threadIdx.x;
    const int lane = tid & 63;
    const int wav  = tid >> 6;
    const int b    = blockIdx.x;

    // Per-lane W row (wave 0 uses it): sigmoid(nw[lane][c]) * gain[lane]/64
    float wReg[NCLUST];
    {
        const float g = gain[lane] * (1.0f / 64.0f);
#pragma unroll
        for (int k = 0; k < 16; k++) {
            float4 w4 = *(const float4*)(nw + lane * NCLUST + 4 * k);
            wReg[4*k+0] = g / (1.0f + expf(-w4.x));
            wReg[4*k+1] = g / (1.0f + expf(-w4.y));
            wReg[4*k+2] = g / (1.0f + expf(-w4.z));
            wReg[4*k+3] = g / (1.0f + expf(-w4.w));
        }
    }
    const float beta_m = 1.0f / (1.0f + expf(-bm_raw[0]));
    const float beta_s = 1.0f / (1.0f + expf(-bs_raw[0]));
    const float ombm   = 1.0f - beta_m;
    const float vreset = -0.1f;

    float v_[4], is_[4], th_[4];
    int   r_[4];
#pragma unroll
    for (int j = 0; j < 4; j++) {
        v_[j] = 0.f; is_[j] = 0.f; r_[j] = 0;
        th_[j] = threshold[tid + j * 1024];
    }

    const size_t strideT = (size_t)BATCH * DIM;
    const float* xp = x_in + (size_t)b * DIM + tid;

    float xA[4], xB[4];
#pragma unroll
    for (int j = 0; j < 4; j++) {
        xA[j] = xp[j * 1024];
        xB[j] = xp[strideT + j * 1024];
    }

    if (tid < NCLUST) sCnt[tid] = 0u;
    __syncthreads();

    float casc = 0.f;
    float* const gc = gCasc + (size_t)b * NCLUST + lane;   // + t*B*NC per step

#define ASTEP(T_, XC)                                                         \
    {                                                                         \
        unsigned int cnt = 0;                                                 \
        _Pragma("unroll")                                                     \
        for (int j = 0; j < 4; j++) {                                         \
            float s = lif_step(XC[j], casc, th_[j], beta_s, beta_m, ombm,     \
                               vreset, v_[j], is_[j], r_[j]);                 \
            cnt += (s != 0.0f) ? 1u : 0u;                                     \
        }                                                                     \
        if (cnt) atomicAdd(&sCnt[lane], cnt);                                 \
        if ((T_) + 2 < TSTEPS) {                                              \
            const float* xf = xp + (size_t)((T_) + 2) * strideT;              \
            _Pragma("unroll")                                                 \
            for (int j = 0; j < 4; j++) XC[j] = xf[j * 1024];                 \
        }                                                                     \
        BAR();                                                                \
        if (wav == 0) {                                                       \
            float a0 = 0.f, a1 = 0.f, a2 = 0.f, a3 = 0.f;                     \
            _Pragma("unroll")                                                 \
            for (int k = 0; k < 16; k++) {                                    \
                uint4 c4 = *(const uint4*)&sCnt[4 * k];                       \
                a0 += (float)c4.x * wReg[4*k+0];                              \
                a1 += (float)c4.y * wReg[4*k+1];                              \
                a2 += (float)c4.z * wReg[4*k+2];                              \
                a3 += (float)c4.w * wReg[4*k+3];                              \
            }                                                                 \
            float cv = (a0 + a1) + (a2 + a3);                                 \
            sCasc[lane] = cv;                                                 \
            gc[(size_t)(T_) * BATCH * NCLUST] = cv;   /* fire-and-forget */   \
            sCnt[lane] = 0u;    /* after the reads above (in-wave order) */   \
        }                                                                     \
        BAR();                                                                \
        casc = sCasc[lane];                                                   \
    }

    for (int t = 0; t < TSTEPS; t += 2) {
        ASTEP(t,     xA)
        ASTEP(t + 1, xB)
    }
#undef ASTEP
}

// ---------------- Kernel B: embarrassingly-parallel replay ----------------
// 512 blocks x 256 thr, 2 neurons/thread (float2 I/O), full chip. Stages the
// row's 32x64 cascade table in LDS, then runs the identical recursion and
// streams s/v out at full-device bandwidth. The cascade registers are a
// SINGLE sequential pair (casc0, casc1) — step t+1 consumes the cascade
// produced at step t (round-8 bug: parity-split cascade skipped a step).
__global__ __launch_bounds__(256)
void alif_replay(const float* __restrict__ x_in,      // (T,B,D)
                 const float* __restrict__ threshold, // (D)
                 const float* __restrict__ bm_raw,
                 const float* __restrict__ bs_raw,
                 const float* __restrict__ gCasc,     // (T,B,NC)
                 float* __restrict__ out_s,           // (T,B,D)
                 float* __restrict__ out_v)           // (T,B,D)
{
    __shared__ __align__(8) float sC[TSTEPS * NCLUST];   // 8 KB

    const int tid  = threadIdx.x;
    const int b    = blockIdx.x >> 3;
    const int part = blockIdx.x & 7;
    const int d0   = part * 512 + 2 * tid;
    const int c0   = d0 & 63;                            // even

    for (int i = tid; i < TSTEPS * NCLUST; i += 256)
        sC[i] = gCasc[((size_t)(i >> 6) * BATCH + b) * NCLUST + (i & 63)];

    const float beta_m = 1.0f / (1.0f + expf(-bm_raw[0]));
    const float beta_s = 1.0f / (1.0f + expf(-bs_raw[0]));
    const float ombm   = 1.0f - beta_m;
    const float vreset = -0.1f;

    const float th0 = threshold[d0];
    const float th1 = threshold[d0 + 1];
    float v0 = 0.f, is0 = 0.f, v1 = 0.f, is1 = 0.f;
    int   r0 = 0, r1 = 0;

    const size_t strideT = (size_t)BATCH * DIM;
    const float* xp = x_in  + (size_t)b * DIM + d0;
    float*       sp = out_s + (size_t)b * DIM + d0;
    float*       vp = out_v + (size_t)b * DIM + d0;

    float2 xA = *(const float2*)xp;
    float2 xB = *(const float2*)(xp + strideT);

    __syncthreads();

    float casc0 = 0.f, casc1 = 0.f;    // cascade applied at this step (from t-1)

#define BSTEP(T_, XC)                                                         \
    {                                                                         \
        float s0 = lif_step(XC.x, casc0, th0, beta_s, beta_m, ombm, vreset,   \
                            v0, is0, r0);                                     \
        float s1 = lif_step(XC.y, casc1, th1, beta_s, beta_m, ombm, vreset,   \
                            v1, is1, r1);                                     \
        *(float2*)(sp + (size_t)(T_) * strideT) = make_float2(s0, s1);        \
        *(float2*)(vp + (size_t)(T_) * strideT) = make_float2(v0, v1);        \
        if ((T_) + 2 < TSTEPS)                                                \
            XC = *(const float2*)(xp + (size_t)((T_) + 2) * strideT);         \
        float2 cn = *(const float2*)&sC[(T_) * NCLUST + c0];                  \
        casc0 = cn.x; casc1 = cn.y;   /* cascade produced at step T_ */       \
    }

    for (int t = 0; t < TSTEPS; t += 2) {
        BSTEP(t,     xA)
        BSTEP(t + 1, xB)
    }
#undef BSTEP
}

extern "C" void kernel_launch(void* const* d_in, const int* in_sizes, int n_in,
                              void* d_out, int out_size, void* d_ws, size_t ws_size,
                              hipStream_t stream) {
    const float* x  = (const float*)d_in[0];
    const float* th = (const float*)d_in[1];
    const float* bm = (const float*)d_in[2];
    const float* bs = (const float*)d_in[3];
    const float* nw = (const float*)d_in[4];
    const float* gn = (const float*)d_in[5];
    float* out_s = (float*)d_out;
    float* out_v = out_s + (size_t)TSTEPS * BATCH * DIM;

    float* gCasc = (float*)d_ws;   // (T,B,NC) f32 = 512 KB; fully rewritten by
                                   // alif_casc before alif_replay reads it (no
                                   // memset, no cross-replay state).

    hipLaunchKernelGGL(alif_casc, dim3(BATCH), dim3(1024), 0, stream,
                       x, th, bm, bs, nw, gn, gCasc);
    hipLaunchKernelGGL(alif_replay, dim3(BATCH * 8), dim3(256), 0, stream,
                       x, th, bm, bs, gCasc, out_s, out_v);
}